// Round 7
// baseline (134.322 us; speedup 1.0000x reference)
//
#include <hip/hip_runtime.h>

// CGLayer: MAX_L=2, B=2, N=256, TAU=16 — 3-kernel pipeline.
// Identity: sum_j of edge-level CG(rep, sph) commutes with the j-sum because rep is
// broadcast along j => per-node work after S[bi][m2] = sum_j s[bi][j][m2].
// k_prep: vmp + S + CG table + wnl transpose.
// k_main: node CG + wnl mix (weights reg-prefetched), rel CG + wrel mix (LDS),
//         per-block partial sums via PLAIN stores (no same-address atomics).
// k_norm: per-block redundant reduce of partials + normalize.

#define TAU 16

// ws layout (floats)
#define CG_OFF   0        // 615
#define PART_OFF 768      // 3*512 per-block partial sums [l][bi]
#define VMP_OFF  4096     // 512*144
#define S_OFF    77824    // 512*16 (9 used)
#define WT_OFF   86016    // 15*4096 transposed wnl tiles [tile][tc][cd]

__constant__ double g_FACT[8] = {1.0,1.0,2.0,6.0,24.0,120.0,720.0,5040.0};
__constant__ int g_TRI[15][3] = {
  {0,0,0},{0,1,1},{0,2,2},{1,0,1},{1,1,0},{1,1,1},{1,1,2},{1,2,1},{1,2,2},
  {2,0,2},{2,1,1},{2,1,2},{2,2,0},{2,2,1},{2,2,2}};
__constant__ int g_TRI_OFF[16] = {0,1,10,35,44,53,80,125,170,245,270,315,390,415,490,615};

constexpr int OFF3[27] = {           // [l1*9 + l2*3 + l] -> cg table offset
  0,-1,-1,  -1,1,-1,   -1,-1,10,
  -1,35,-1, 44,53,80,  -1,125,170,
  -1,-1,245,-1,270,315,390,415,490};
constexpr int PAIRS[3][6][2] = {     // (l1,l2) order per output l (reference concat order)
  {{0,0},{1,1},{2,2},{0,0},{0,0},{0,0}},
  {{0,1},{1,0},{1,1},{1,2},{2,1},{2,2}},
  {{0,2},{1,1},{1,2},{2,0},{2,1},{2,2}}};
constexpr int VOFF[3]   = {0,16,64};
constexpr int SOFF[3]   = {0,1,4};
constexpr int OUT_OFF[3]= {0,8192,32768};
constexpr int NPAIR[3]  = {3,6,6};
constexpr int FOFF[9]   = {0,16,32,48,64,80,96,112,128};
constexpr int WROFF[3]  = {0,768,2304};   // wrel LDS offsets

__device__ constexpr int RIDX(int l, int mi){ return l==0 ? 0 : (l==1 ? 1+mi : 4+mi); }

__device__ double cg_coef(int j1,int j2,int j3,int m1,int m2,int m3){
  double pre = sqrt((2.0*j3+1.0)*g_FACT[j3+j1-j2]*g_FACT[j3-j1+j2]*g_FACT[j1+j2-j3]/g_FACT[j1+j2+j3+1]);
  pre *= sqrt(g_FACT[j3+m3]*g_FACT[j3-m3]*g_FACT[j1-m1]*g_FACT[j1+m1]*g_FACT[j2-m2]*g_FACT[j2+m2]);
  int kmin = max(0, max(j2-j3-m1, j1-j3+m2));
  int kmax = min(j1+j2-j3, min(j1-m1, j2+m2));
  double s = 0.0;
  for (int k=kmin;k<=kmax;k++){
    double d = g_FACT[k]*g_FACT[j1+j2-j3-k]*g_FACT[j1-m1-k]*g_FACT[j2+m2-k]*g_FACT[j3-j2+m1+k]*g_FACT[j3-j1-m2+k];
    s += (k & 1) ? (-1.0/d) : (1.0/d);
  }
  return pre*s;
}

// ---------------- K1: vmp + S + CG table + wnl transpose ----------------
__global__ __launch_bounds__(512)
void k_prep(const float* __restrict__ v0, const float* __restrict__ v1, const float* __restrict__ v2,
            const float* __restrict__ s0, const float* __restrict__ s1, const float* __restrict__ s2,
            const float* __restrict__ wnl0, const float* __restrict__ wnl1, const float* __restrict__ wnl2,
            const int* __restrict__ conn, float* __restrict__ ws)
{
  __shared__ float sh_conn[256];
  __shared__ float sh_v[2][144];
  __shared__ float sh_red[4][9];
  const int t = threadIdx.x;
  const int blk = blockIdx.x;

  if (blk < 512) {
    // vmp[bi][f] = sum_j conn[bi,j] * v[b,j,f]; 2 j-halves x 144 feats, 8-acc ILP
    const int bi = blk, b = bi >> 8;
    if (t < 256) sh_conn[t] = (float)conn[((size_t)bi<<8) + t];
    __syncthreads();
    const int h = t >> 8, tt = t & 255;
    if (tt < 144) {
      int l, m, c;
      if (tt < 16)      { l=0; m=0;          c=tt;    }
      else if (tt < 64) { l=1; m=(tt-16)>>4; c=tt&15; }
      else              { l=2; m=(tt-64)>>4; c=tt&15; }
      const float* vl = (l==0) ? v0 : (l==1) ? v1 : v2;
      const int dm = 2*l+1;
      const int stride = dm*TAU;
      const float* base = vl + (((size_t)b*256 + h*128)*dm + m)*TAU + c;
      const float* cr = &sh_conn[h*128];
      float a[8];
      #pragma unroll
      for (int q=0;q<8;q++) a[q]=0.f;
      for (int j=0;j<128;j+=8){
        #pragma unroll
        for (int q=0;q<8;q++) a[q] += cr[j+q]*base[(j+q)*stride];
      }
      sh_v[h][tt] = ((a[0]+a[1])+(a[2]+a[3])) + ((a[4]+a[5])+(a[6]+a[7]));
    }
    __syncthreads();
    if (t < 144) ws[VMP_OFF + (size_t)bi*144 + t] = sh_v[0][t] + sh_v[1][t];
  } else if (blk < 1024) {
    // S[bi][9] = sum_j s_l[bi][j][m] (coalesced, 4-wave shfl reduce)
    const int bi = blk - 512;
    if (t < 256) {
      const float* p0 = s0 + (size_t)bi*256;
      const float* p1 = s1 + (size_t)bi*768;
      const float* p2 = s2 + (size_t)bi*1280;
      float a[9];
      a[0] = p0[t];
      a[1] = p1[3*t+0]; a[2] = p1[3*t+1]; a[3] = p1[3*t+2];
      #pragma unroll
      for (int k=0;k<5;k++) a[4+k] = p2[5*t+k];
      #pragma unroll
      for (int m=0;m<9;m++){
        #pragma unroll
        for (int off=32; off; off>>=1) a[m] += __shfl_xor(a[m], off);
      }
      const int wid = t>>6, lane = t&63;
      if (lane == 0) {
        #pragma unroll
        for (int m=0;m<9;m++) sh_red[wid][m] = a[m];
      }
    }
    __syncthreads();
    if (t < 9) ws[S_OFF + (size_t)(blk-512)*16 + t] = sh_red[0][t]+sh_red[1][t]+sh_red[2][t]+sh_red[3][t];
  } else if (blk < 1039) {
    // transpose one wnl tile: wT[tc][cd] = w[cd][tc]
    const int tile = blk - 1024;   // 0..14: 0-2 wnl0, 3-8 wnl1, 9-14 wnl2
    const float* src = (tile<3) ? (wnl0 + (size_t)tile*4096)
                     : (tile<9) ? (wnl1 + (size_t)(tile-3)*4096)
                                : (wnl2 + (size_t)(tile-9)*4096);
    float* dst = ws + WT_OFF + (size_t)tile*4096;
    if (t < 256) {
      const int cd = t;
      const float4 r0 = *(const float4*)(src + cd*16);
      const float4 r1 = *(const float4*)(src + cd*16 + 4);
      const float4 r2 = *(const float4*)(src + cd*16 + 8);
      const float4 r3 = *(const float4*)(src + cd*16 + 12);
      dst[ 0*256+cd]=r0.x; dst[ 1*256+cd]=r0.y; dst[ 2*256+cd]=r0.z; dst[ 3*256+cd]=r0.w;
      dst[ 4*256+cd]=r1.x; dst[ 5*256+cd]=r1.y; dst[ 6*256+cd]=r1.z; dst[ 7*256+cd]=r1.w;
      dst[ 8*256+cd]=r2.x; dst[ 9*256+cd]=r2.y; dst[10*256+cd]=r2.z; dst[11*256+cd]=r2.w;
      dst[12*256+cd]=r3.x; dst[13*256+cd]=r3.y; dst[14*256+cd]=r3.z; dst[15*256+cd]=r3.w;
    }
  } else {
    // CG table (DP Racah)
    if (t < 128) {
      for (int s = t; s < 615; s += 128) {
        int tr = 0;
        while (s >= g_TRI_OFF[tr+1]) tr++;
        int l1=g_TRI[tr][0], l2=g_TRI[tr][1], l=g_TRI[tr][2];
        int rem = s - g_TRI_OFF[tr];
        int d2 = 2*l2+1, dk = 2*l+1;
        int i1 = rem/(d2*dk); int r2 = rem%(d2*dk); int i2 = r2/dk; int ik = r2%dk;
        int m1=i1-l1, m2=i2-l2, m=ik-l;
        float val = 0.f;
        if (m1+m2 == m) val = (float)cg_coef(l1,l2,l,m1,m2,m);
        ws[CG_OFF + s] = val;
      }
    }
  }
}

// ---------------- K2 helpers ----------------
template<int L, int P>
__device__ __forceinline__ void build_p(float* __restrict__ dst, const float* __restrict__ cgt,
                                        const float (&v_c)[9], const float (&v_d)[9], int t){
  constexpr int l1 = PAIRS[L][P][0], l2 = PAIRS[L][P][1];
  constexpr int d2 = 2*l2+1, dkk = 2*L+1;
  constexpr int coff = OFF3[l1*9+l2*3+L];
  #pragma unroll
  for (int kk=0; kk<dkk; kk++){
    const int m = kk - L;
    float a = 0.f;
    #pragma unroll
    for (int m1=-l1; m1<=l1; m1++){
      const int m2 = m - m1;
      if (m2 >= -l2 && m2 <= l2)
        a += cgt[coff + ((m1+l1)*d2 + (m2+l2))*dkk + kk] * v_c[RIDX(l1,m1+l1)] * v_d[RIDX(l2,m2+l2)];
    }
    dst[kk*256 + t] = a;   // blk[kk][cd=t]
  }
}

template<int DK>
__device__ __forceinline__ void mixr(const float* __restrict__ bb, const float4 w0, const float4 w1,
                                     float (&acc)[DK][2], int ksub){
  #pragma unroll
  for (int k=0;k<DK;k++){
    const float4 bk = *(const float4*)&bb[k*256 + ksub*4];
    acc[k][0] += bk.x*w0.x + bk.y*w0.y + bk.z*w0.z + bk.w*w0.w;
    acc[k][1] += bk.x*w1.x + bk.y*w1.y + bk.z*w1.z + bk.w*w1.w;
  }
}

// one output-l of phase B: build/mix pipeline over pairs, weights reg-prefetched 1 ahead
template<int L>
__device__ __forceinline__ void phaseB(const float* __restrict__ cgt, const float* __restrict__ wt,
                                       const float (&v_c)[9], const float (&v_d)[9],
                                       float* __restrict__ b0, float* __restrict__ b1,
                                       float* __restrict__ sh_mnl, int t, int ksub, int tc0){
  constexpr int NP = NPAIR[L];
  constexpr int DK = 2*L+1;
  float acc[DK][2];
  #pragma unroll
  for (int k=0;k<DK;k++){ acc[k][0]=0.f; acc[k][1]=0.f; }
  const float* wbase = wt + (size_t)tc0*256 + ksub*4;

  float4 w0c = *(const float4*)(wbase);
  float4 w1c = *(const float4*)(wbase + 256);
  if (t < 256) build_p<L,0>(b0, cgt, v_c, v_d, t);
  __syncthreads();                               // b0 + pair0 weights ready

  float4 w0n, w1n;
  // p = 0 (mix b0)
  if constexpr (NP > 1){
    w0n = *(const float4*)(wbase + 4096);        // issue pair1 weights EARLY
    w1n = *(const float4*)(wbase + 4096 + 256);
    if (t < 256) build_p<L,1>(b1, cgt, v_c, v_d, t);
  }
  mixr<DK>(b0, w0c, w1c, acc, ksub);
  __syncthreads();
  if constexpr (NP > 1){
    w0c = w0n; w1c = w1n;
    // p = 1 (mix b1)
    if constexpr (NP > 2){
      w0n = *(const float4*)(wbase + 2*4096);
      w1n = *(const float4*)(wbase + 2*4096 + 256);
      if (t < 256) build_p<L,2>(b0, cgt, v_c, v_d, t);
    }
    mixr<DK>(b1, w0c, w1c, acc, ksub);
    __syncthreads();
    w0c = w0n; w1c = w1n;
    // p = 2 (mix b0)
    if constexpr (NP > 3){
      w0n = *(const float4*)(wbase + 3*4096);
      w1n = *(const float4*)(wbase + 3*4096 + 256);
      if (t < 256) build_p<L,3>(b1, cgt, v_c, v_d, t);
    }
    mixr<DK>(b0, w0c, w1c, acc, ksub);
    __syncthreads();
    if constexpr (NP > 3){
      w0c = w0n; w1c = w1n;
      // p = 3 (mix b1)
      w0n = *(const float4*)(wbase + 4*4096);
      w1n = *(const float4*)(wbase + 4*4096 + 256);
      if (t < 256) build_p<L,4>(b0, cgt, v_c, v_d, t);
      mixr<DK>(b1, w0c, w1c, acc, ksub);
      __syncthreads();
      w0c = w0n; w1c = w1n;
      // p = 4 (mix b0)
      w0n = *(const float4*)(wbase + 5*4096);
      w1n = *(const float4*)(wbase + 5*4096 + 256);
      if (t < 256) build_p<L,5>(b1, cgt, v_c, v_d, t);
      mixr<DK>(b0, w0c, w1c, acc, ksub);
      __syncthreads();
      w0c = w0n; w1c = w1n;
      // p = 5 (mix b1)
      mixr<DK>(b1, w0c, w1c, acc, ksub);
      __syncthreads();
    }
  }
  // butterfly over the 64 K-chunk lanes
  #pragma unroll
  for (int k=0;k<DK;k++){
    #pragma unroll
    for (int off=32; off; off>>=1){
      acc[k][0] += __shfl_xor(acc[k][0], off);
      acc[k][1] += __shfl_xor(acc[k][1], off);
    }
  }
  if (ksub == 0) {
    #pragma unroll
    for (int k=0;k<DK;k++){
      sh_mnl[VOFF[L] + k*16 + tc0    ] = acc[k][0];
      sh_mnl[VOFF[L] + k*16 + tc0 + 1] = acc[k][1];
    }
  }
}

// ---------------- K2: per-node CG products + mixing + partial sums ----------------
__global__ __launch_bounds__(512, 4)
void k_main(const float* __restrict__ wrel0, const float* __restrict__ wrel1, const float* __restrict__ wrel2,
            const float* __restrict__ ws, float* __restrict__ out, float* __restrict__ part)
{
  __shared__ __align__(16) float sh_b0[1280];   // double-buffered CG blocks [dk][256]
  __shared__ __align__(16) float sh_b1[1280];
  __shared__ float sh_wrel[3840];               // all wrel weights, staged once
  __shared__ float sh_mnl[144];
  __shared__ float sh_S[9];
  __shared__ float sh_rel[6*144];               // [p][f144]
  __shared__ float sh_acc[144];
  __shared__ float sh_lred[48];

  const int t  = threadIdx.x;
  const int bi = blockIdx.x;
  const float* __restrict__ cgt = ws + CG_OFF;

  // stage wrel into LDS (coalesced) — consumed in phase C
  for (int i=t; i<3840; i+=512){
    float v;
    if (i < 768)       v = wrel0[i];
    else if (i < 2304) v = wrel1[i-768];
    else               v = wrel2[i-2304];
    sh_wrel[i] = v;
  }
  // per-thread vmp fragments (registers only)
  const int bc = (t>>4)&15, bd = t&15;
  float v_c[9], v_d[9];
  {
    const float* vb = ws + VMP_OFF + (size_t)bi*144;
    #pragma unroll
    for (int r=0;r<9;r++){ v_c[r] = vb[FOFF[r]+bc]; v_d[r] = vb[FOFF[r]+bd]; }
  }
  if (t < 9) sh_S[t] = ws[S_OFF + (size_t)bi*16 + t];

  const int tg = t>>6, ksub = t&63;  // wave = tc-pair, lane = K-chunk
  const int tc0 = tg*2;

  // -------- Phase B --------
  phaseB<0>(cgt, ws + WT_OFF +     0, v_c, v_d, sh_b0, sh_b1, sh_mnl, t, ksub, tc0);
  phaseB<1>(cgt, ws + WT_OFF + 12288, v_c, v_d, sh_b0, sh_b1, sh_mnl, t, ksub, tc0);
  phaseB<2>(cgt, ws + WT_OFF + 36864, v_c, v_d, sh_b0, sh_b1, sh_mnl, t, ksub, tc0);
  __syncthreads();   // sh_mnl complete

  // -------- Phase C: rel-level CG (j-summed sph) + wrel mixing, 2 barriers --------
  int l=0, f=0;
  if (t < 16)       { l=0; f=t;    }
  else if (t < 64)  { l=1; f=t-16; }
  else if (t < 144) { l=2; f=t-64; }
  const int k = f>>4, tc = f&15;

  if (t < 144) {
    const int np = NPAIR[l];
    #pragma unroll
    for (int p=0; p<6; p++) {
      if (p < np) {
        const int l1 = PAIRS[l][p][0], l2 = PAIRS[l][p][1];
        const int d2 = 2*l2+1;
        const int coff = OFF3[l1*9+l2*3+l];
        const int dk = 2*l+1;
        const int m = k - l;
        float a = 0.f;
        const int lo = (-l1 > m-l2) ? -l1 : m-l2;
        const int hi = ( l1 < m+l2) ?  l1 : m+l2;
        #pragma unroll
        for (int m1=-2; m1<=2; m1++) {
          if (m1 >= lo && m1 <= hi) {
            const int m2 = m - m1;
            const float C = cgt[coff + ((m1+l1)*d2 + (m2+l2))*dk + k];
            a += C * sh_mnl[VOFF[l1] + (m1+l1)*TAU + tc] * sh_S[SOFF[l2] + (m2+l2)];
          }
        }
        sh_rel[p*144 + t] = a;
      }
    }
  }
  __syncthreads();
  if (t < 144) {
    const int np = NPAIR[l];
    float acc = 0.f;
    #pragma unroll
    for (int p=0; p<6; p++) {
      if (p < np) {
        const float* rrow = &sh_rel[p*144 + VOFF[l] + k*16];
        const float* wrow = &sh_wrel[WROFF[l] + p*256 + tc];
        #pragma unroll
        for (int c=0; c<16; c++)
          acc += rrow[c] * wrow[c*16];
      }
    }
    out[OUT_OFF[l] + ((size_t)bi*(2*l+1) + k)*TAU + tc] = acc;
    sh_acc[t] = acc;
  }
  __syncthreads();
  if (t < 48) {
    const int ll = t>>4, q = t&15;
    const int n = 2*ll+1;
    float a = 0.f;
    for (int i=0;i<n;i++) a += sh_acc[VOFF[ll] + i*16 + q];
    sh_lred[t] = a;
  }
  __syncthreads();
  if (t < 3) {
    float a = 0.f;
    #pragma unroll
    for (int q=0;q<16;q++) a += sh_lred[t*16+q];
    part[t*512 + bi] = a;   // plain store — zero contention
  }
}

// ---------------- K3: redundant partial-reduce + normalize ----------------
__global__ __launch_bounds__(256)
void k_norm(float* __restrict__ out, const float* __restrict__ part){
  __shared__ float sh_r[96];
  __shared__ float sh_d[3];
  const int t = threadIdx.x;
  if (t < 96){
    const int l = t>>5, q = t&31;
    const float* p = part + l*512 + q*16;
    float a=0.f;
    #pragma unroll
    for (int i=0;i<16;i++) a += p[i];
    sh_r[t] = a;
  }
  __syncthreads();
  if (t < 3){
    float a=0.f;
    const float* r = &sh_r[t*32];
    #pragma unroll
    for (int i=0;i<32;i++) a += r[i];
    sh_d[t] = a;
  }
  __syncthreads();
  const int idx = blockIdx.x*256 + t;
  if (idx < 73728){
    const int l = (idx < 8192) ? 0 : (idx < 32768) ? 1 : 2;
    out[idx] = out[idx] / sh_d[l];
  }
}

extern "C" void kernel_launch(void* const* d_in, const int* in_sizes, int n_in,
                              void* d_out, int out_size, void* d_ws, size_t ws_size,
                              hipStream_t stream) {
  // setup_inputs order: v0,s0,wnl0,wrel0, v1,s1,wnl1,wrel1, v2,s2,wnl2,wrel2, conn
  const float* v0    = (const float*)d_in[0];
  const float* s0    = (const float*)d_in[1];
  const float* wnl0  = (const float*)d_in[2];
  const float* wrel0 = (const float*)d_in[3];
  const float* v1    = (const float*)d_in[4];
  const float* s1    = (const float*)d_in[5];
  const float* wnl1  = (const float*)d_in[6];
  const float* wrel1 = (const float*)d_in[7];
  const float* v2    = (const float*)d_in[8];
  const float* s2    = (const float*)d_in[9];
  const float* wnl2  = (const float*)d_in[10];
  const float* wrel2 = (const float*)d_in[11];
  const int*   conn  = (const int*)d_in[12];
  float* out = (float*)d_out;
  float* ws  = (float*)d_ws;
  float* part = ws + PART_OFF;

  k_prep<<<1040, 512, 0, stream>>>(v0, v1, v2, s0, s1, s2,
                                   wnl0, wnl1, wnl2, conn, ws);
  k_main<<<512, 512, 0, stream>>>(wrel0, wrel1, wrel2, ws, out, part);
  k_norm<<<288, 256, 0, stream>>>(out, part);
}

// Round 8
// 109.690 us; speedup vs baseline: 1.2246x; 1.2246x over previous
//
#include <hip/hip_runtime.h>

// CGLayer: MAX_L=2, B=2, N=256, TAU=16 — 3-kernel pipeline.
// Identity: sum_j of edge-level CG(rep, sph) commutes with the j-sum because rep is
// broadcast along j => per-node work after S[bi][m2] = sum_j s[bi][j][m2].
// Round-8: CG coefficients are COMPILE-TIME constants (constexpr Racah); phase B is
// one build+mix step per output-l (4 barriers instead of 18).

#define TAU 16

// ws layout (floats)
#define PART_OFF 768      // 3*512 per-block partial sums [l][bi]
#define VMP_OFF  4096     // 512*144
#define S_OFF    77824    // 512*16 (9 used)
#define WT_OFF   86016    // 15*4096 transposed wnl tiles [tile][tc][cd]

// ---------------- compile-time CG table ----------------
constexpr double cfact(int n){ double r=1.0; for(int i=2;i<=n;i++) r*=i; return r; }
constexpr double csqrt(double x){
  if (x<=0.0) return 0.0;
  double g = x<1.0 ? 1.0 : x;
  for (int i=0;i<80;i++) g = 0.5*(g + x/g);
  return g;
}
constexpr double cg_c(int j1,int j2,int j3,int m1,int m2,int m3){
  if (m1+m2 != m3) return 0.0;
  double pre = csqrt((2.0*j3+1.0)*cfact(j3+j1-j2)*cfact(j3-j1+j2)*cfact(j1+j2-j3)/cfact(j1+j2+j3+1));
  pre *= csqrt(cfact(j3+m3)*cfact(j3-m3)*cfact(j1-m1)*cfact(j1+m1)*cfact(j2-m2)*cfact(j2+m2));
  int kmin = 0;
  if (j2-j3-m1 > kmin) kmin = j2-j3-m1;
  if (j1-j3+m2 > kmin) kmin = j1-j3+m2;
  int kmax = j1+j2-j3;
  if (j1-m1 < kmax) kmax = j1-m1;
  if (j2+m2 < kmax) kmax = j2+m2;
  double s = 0.0;
  for (int k=kmin;k<=kmax;k++){
    double d = cfact(k)*cfact(j1+j2-j3-k)*cfact(j1-m1-k)*cfact(j2+m2-k)*cfact(j3-j2+m1+k)*cfact(j3-j1-m2+k);
    s += (k & 1) ? (-1.0/d) : (1.0/d);
  }
  return pre*s;
}
struct CGTab { float v[615]; };
constexpr CGTab gen_cg(){
  CGTab t{};
  const int TRI[15][3] = {
    {0,0,0},{0,1,1},{0,2,2},{1,0,1},{1,1,0},{1,1,1},{1,1,2},{1,2,1},{1,2,2},
    {2,0,2},{2,1,1},{2,1,2},{2,2,0},{2,2,1},{2,2,2}};
  int off = 0;
  for (int tr=0;tr<15;tr++){
    const int l1=TRI[tr][0], l2=TRI[tr][1], l=TRI[tr][2];
    for (int i1=0;i1<2*l1+1;i1++)
      for (int i2=0;i2<2*l2+1;i2++)
        for (int ik=0;ik<2*l+1;ik++)
          t.v[off++] = (float)cg_c(l1,l2,l,i1-l1,i2-l2,ik-l);
  }
  return t;
}
constexpr CGTab CG = gen_cg();

constexpr int OFF3[27] = {           // [l1*9 + l2*3 + l] -> cg table offset
  0,-1,-1,  -1,1,-1,   -1,-1,10,
  -1,35,-1, 44,53,80,  -1,125,170,
  -1,-1,245,-1,270,315,390,415,490};
constexpr int PAIRS[3][6][2] = {     // (l1,l2) order per output l (reference concat order)
  {{0,0},{1,1},{2,2},{0,0},{0,0},{0,0}},
  {{0,1},{1,0},{1,1},{1,2},{2,1},{2,2}},
  {{0,2},{1,1},{1,2},{2,0},{2,1},{2,2}}};
constexpr int VOFF[3]   = {0,16,64};
constexpr int SOFF[3]   = {0,1,4};
constexpr int OUT_OFF[3]= {0,8192,32768};
constexpr int NPAIR[3]  = {3,6,6};
constexpr int FOFF[9]   = {0,16,32,48,64,80,96,112,128};
constexpr int WROFF[3]  = {0,768,2304};   // wrel LDS offsets
constexpr int WTL[3]    = {0,12288,36864};// per-l offset into transposed wnl region

__device__ constexpr int RIDX(int l, int mi){ return l==0 ? 0 : (l==1 ? 1+mi : 4+mi); }

// ---------------- K1: vmp + S + wnl transpose ----------------
__global__ __launch_bounds__(512)
void k_prep(const float* __restrict__ v0, const float* __restrict__ v1, const float* __restrict__ v2,
            const float* __restrict__ s0, const float* __restrict__ s1, const float* __restrict__ s2,
            const float* __restrict__ wnl0, const float* __restrict__ wnl1, const float* __restrict__ wnl2,
            const int* __restrict__ conn, float* __restrict__ ws)
{
  __shared__ float sh_conn[256];
  __shared__ float sh_v[2][144];
  __shared__ float sh_red[4][9];
  const int t = threadIdx.x;
  const int blk = blockIdx.x;

  if (blk < 512) {
    // vmp[bi][f] = sum_j conn[bi,j] * v[b,j,f]; 2 j-halves x 144 feats, 8-acc ILP
    const int bi = blk, b = bi >> 8;
    if (t < 256) sh_conn[t] = (float)conn[((size_t)bi<<8) + t];
    __syncthreads();
    const int h = t >> 8, tt = t & 255;
    if (tt < 144) {
      int l, m, c;
      if (tt < 16)      { l=0; m=0;          c=tt;    }
      else if (tt < 64) { l=1; m=(tt-16)>>4; c=tt&15; }
      else              { l=2; m=(tt-64)>>4; c=tt&15; }
      const float* vl = (l==0) ? v0 : (l==1) ? v1 : v2;
      const int dm = 2*l+1;
      const int stride = dm*TAU;
      const float* base = vl + (((size_t)b*256 + h*128)*dm + m)*TAU + c;
      const float* cr = &sh_conn[h*128];
      float a[8];
      #pragma unroll
      for (int q=0;q<8;q++) a[q]=0.f;
      for (int j=0;j<128;j+=8){
        #pragma unroll
        for (int q=0;q<8;q++) a[q] += cr[j+q]*base[(j+q)*stride];
      }
      sh_v[h][tt] = ((a[0]+a[1])+(a[2]+a[3])) + ((a[4]+a[5])+(a[6]+a[7]));
    }
    __syncthreads();
    if (t < 144) ws[VMP_OFF + (size_t)bi*144 + t] = sh_v[0][t] + sh_v[1][t];
  } else if (blk < 1024) {
    // S[bi][9] = sum_j s_l[bi][j][m] (coalesced, 4-wave shfl reduce)
    const int bi = blk - 512;
    if (t < 256) {
      const float* p0 = s0 + (size_t)bi*256;
      const float* p1 = s1 + (size_t)bi*768;
      const float* p2 = s2 + (size_t)bi*1280;
      float a[9];
      a[0] = p0[t];
      a[1] = p1[3*t+0]; a[2] = p1[3*t+1]; a[3] = p1[3*t+2];
      #pragma unroll
      for (int k=0;k<5;k++) a[4+k] = p2[5*t+k];
      #pragma unroll
      for (int m=0;m<9;m++){
        #pragma unroll
        for (int off=32; off; off>>=1) a[m] += __shfl_xor(a[m], off);
      }
      const int wid = t>>6, lane = t&63;
      if (lane == 0) {
        #pragma unroll
        for (int m=0;m<9;m++) sh_red[wid][m] = a[m];
      }
    }
    __syncthreads();
    if (t < 9) ws[S_OFF + (size_t)(blk-512)*16 + t] = sh_red[0][t]+sh_red[1][t]+sh_red[2][t]+sh_red[3][t];
  } else {
    // transpose one wnl tile: wT[tc][cd] = w[cd][tc]
    const int tile = blk - 1024;   // 0..14
    const float* src = (tile<3) ? (wnl0 + (size_t)tile*4096)
                     : (tile<9) ? (wnl1 + (size_t)(tile-3)*4096)
                                : (wnl2 + (size_t)(tile-9)*4096);
    float* dst = ws + WT_OFF + (size_t)tile*4096;
    if (t < 256) {
      const int cd = t;
      const float4 r0 = *(const float4*)(src + cd*16);
      const float4 r1 = *(const float4*)(src + cd*16 + 4);
      const float4 r2 = *(const float4*)(src + cd*16 + 8);
      const float4 r3 = *(const float4*)(src + cd*16 + 12);
      dst[ 0*256+cd]=r0.x; dst[ 1*256+cd]=r0.y; dst[ 2*256+cd]=r0.z; dst[ 3*256+cd]=r0.w;
      dst[ 4*256+cd]=r1.x; dst[ 5*256+cd]=r1.y; dst[ 6*256+cd]=r1.z; dst[ 7*256+cd]=r1.w;
      dst[ 8*256+cd]=r2.x; dst[ 9*256+cd]=r2.y; dst[10*256+cd]=r2.z; dst[11*256+cd]=r2.w;
      dst[12*256+cd]=r3.x; dst[13*256+cd]=r3.y; dst[14*256+cd]=r3.z; dst[15*256+cd]=r3.w;
    }
  }
}

// ---------------- K2 helpers ----------------
// build one pair's blk rows; all CG values are compile-time float literals
template<int L, int P>
__device__ __forceinline__ void build_p(float* __restrict__ dst,
                                        const float (&v_c)[9], const float (&v_d)[9], int tt){
  constexpr int l1 = PAIRS[L][P][0], l2 = PAIRS[L][P][1];
  constexpr int d2 = 2*l2+1, dkk = 2*L+1;
  constexpr int coff = OFF3[l1*9+l2*3+L];
  #pragma unroll
  for (int kk=0; kk<dkk; kk++){
    const int m = kk - L;
    float a = 0.f;
    #pragma unroll
    for (int m1=-l1; m1<=l1; m1++){
      const int m2 = m - m1;
      if (m2 >= -l2 && m2 <= l2){
        constexpr int base = coff;   // force constexpr context
        const float C = CG.v[base + ((m1+l1)*d2 + (m2+l2))*dkk + kk];
        a += C * v_c[RIDX(l1,m1+l1)] * v_d[RIDX(l2,m2+l2)];
      }
    }
    dst[(P*dkk + kk)*256 + tt] = a;
  }
}

// one output-l of phase B: prefetch all pair weights -> build ALL pairs -> one
// barrier -> mix all pairs (no inner barriers) -> wave butterfly -> sh_mnl
template<int L>
__device__ __forceinline__ void phaseB2(const float* __restrict__ wt,
                                        const float (&v_c)[9], const float (&v_d)[9],
                                        float* __restrict__ sh_bm, float* __restrict__ sh_mnl,
                                        int t, int ksub, int tc0){
  constexpr int NP = NPAIR[L];
  constexpr int DK = 2*L+1;
  // prefetch all pair weights for this l (registers; drained at the barrier below,
  // hidden under the build VALU work)
  const float* wb = wt + (size_t)tc0*256 + ksub*4;
  float4 w0[NP], w1[NP];
  #pragma unroll
  for (int p=0;p<NP;p++){
    w0[p] = *(const float4*)(wb + (size_t)p*4096);
    w1[p] = *(const float4*)(wb + (size_t)p*4096 + 256);
  }
  // build all pairs (half 0: p<3, half 1: p>=3)
  const int tt = t & 255;
  if constexpr (NP == 3) {
    if (t < 256){ build_p<L,0>(sh_bm,v_c,v_d,tt); build_p<L,1>(sh_bm,v_c,v_d,tt); build_p<L,2>(sh_bm,v_c,v_d,tt); }
  } else {
    if (t < 256){ build_p<L,0>(sh_bm,v_c,v_d,tt); build_p<L,1>(sh_bm,v_c,v_d,tt); build_p<L,2>(sh_bm,v_c,v_d,tt); }
    else        { build_p<L,3>(sh_bm,v_c,v_d,tt); build_p<L,4>(sh_bm,v_c,v_d,tt); build_p<L,5>(sh_bm,v_c,v_d,tt); }
  }
  __syncthreads();     // build visible + weights drained
  float acc[DK][2];
  #pragma unroll
  for (int k=0;k<DK;k++){ acc[k][0]=0.f; acc[k][1]=0.f; }
  #pragma unroll
  for (int p=0;p<NP;p++){
    #pragma unroll
    for (int k=0;k<DK;k++){
      const float4 bk = *(const float4*)&sh_bm[(p*DK+k)*256 + ksub*4];
      acc[k][0] += bk.x*w0[p].x + bk.y*w0[p].y + bk.z*w0[p].z + bk.w*w0[p].w;
      acc[k][1] += bk.x*w1[p].x + bk.y*w1[p].y + bk.z*w1[p].z + bk.w*w1[p].w;
    }
  }
  // butterfly over the 64 K-chunk lanes
  #pragma unroll
  for (int k=0;k<DK;k++){
    #pragma unroll
    for (int off=32; off; off>>=1){
      acc[k][0] += __shfl_xor(acc[k][0], off);
      acc[k][1] += __shfl_xor(acc[k][1], off);
    }
  }
  if (ksub == 0) {
    #pragma unroll
    for (int k=0;k<DK;k++){
      sh_mnl[VOFF[L] + k*16 + tc0    ] = acc[k][0];
      sh_mnl[VOFF[L] + k*16 + tc0 + 1] = acc[k][1];
    }
  }
  __syncthreads();     // mix reads done; next l may overwrite sh_bm; sh_mnl visible
}

// ---------------- K2: per-node CG products + mixing + partial sums ----------------
__global__ __launch_bounds__(512, 2)
void k_main(const float* __restrict__ wrel0, const float* __restrict__ wrel1, const float* __restrict__ wrel2,
            const float* __restrict__ ws, float* __restrict__ out, float* __restrict__ part)
{
  __shared__ __align__(16) float sh_bm[30*256];  // CG blocks for one l (30 rows max)
  __shared__ float sh_wrel[3840];                // all wrel weights, staged once
  __shared__ float sh_mnl[144];
  __shared__ float sh_S[9];
  __shared__ float sh_rel[6*144];                // [p][f144]
  __shared__ float sh_acc[144];
  __shared__ float sh_lred[48];

  const int t  = threadIdx.x;
  const int bi = blockIdx.x;

  // stage wrel into LDS (coalesced) — consumed in phase C, far behind many barriers
  for (int i=t; i<3840; i+=512){
    float v;
    if (i < 768)       v = wrel0[i];
    else if (i < 2304) v = wrel1[i-768];
    else               v = wrel2[i-2304];
    sh_wrel[i] = v;
  }
  // per-thread vmp fragments (registers only)
  const int bc = (t>>4)&15, bd = t&15;
  float v_c[9], v_d[9];
  {
    const float* vb = ws + VMP_OFF + (size_t)bi*144;
    #pragma unroll
    for (int r=0;r<9;r++){ v_c[r] = vb[FOFF[r]+bc]; v_d[r] = vb[FOFF[r]+bd]; }
  }
  if (t < 9) sh_S[t] = ws[S_OFF + (size_t)bi*16 + t];

  const int tg = t>>6, ksub = t&63;  // wave = tc-pair, lane = K-chunk
  const int tc0 = tg*2;

  // -------- Phase B: 2 barriers per l --------
  phaseB2<0>(ws + WT_OFF + WTL[0], v_c, v_d, sh_bm, sh_mnl, t, ksub, tc0);
  phaseB2<1>(ws + WT_OFF + WTL[1], v_c, v_d, sh_bm, sh_mnl, t, ksub, tc0);
  phaseB2<2>(ws + WT_OFF + WTL[2], v_c, v_d, sh_bm, sh_mnl, t, ksub, tc0);

  // -------- Phase C: rel-level CG (j-summed sph) + wrel mixing --------
  int l=0, f=0;
  if (t < 16)       { l=0; f=t;    }
  else if (t < 64)  { l=1; f=t-16; }
  else if (t < 144) { l=2; f=t-64; }
  const int k = f>>4, tc = f&15;

  if (t < 144) {
    const int np = NPAIR[l];
    #pragma unroll
    for (int p=0; p<6; p++) {
      if (p < np) {
        const int l1 = PAIRS[l][p][0], l2 = PAIRS[l][p][1];
        const int d2 = 2*l2+1;
        const int coff = OFF3[l1*9+l2*3+l];
        const int dk = 2*l+1;
        const int m = k - l;
        float a = 0.f;
        const int lo = (-l1 > m-l2) ? -l1 : m-l2;
        const int hi = ( l1 < m+l2) ?  l1 : m+l2;
        #pragma unroll
        for (int m1=-2; m1<=2; m1++) {
          if (m1 >= lo && m1 <= hi) {
            const int m2 = m - m1;
            const float C = CG.v[coff + ((m1+l1)*d2 + (m2+l2))*dk + k];
            a += C * sh_mnl[VOFF[l1] + (m1+l1)*TAU + tc] * sh_S[SOFF[l2] + (m2+l2)];
          }
        }
        sh_rel[p*144 + t] = a;
      }
    }
  }
  __syncthreads();
  if (t < 144) {
    const int np = NPAIR[l];
    float acc = 0.f;
    #pragma unroll
    for (int p=0; p<6; p++) {
      if (p < np) {
        const float* rrow = &sh_rel[p*144 + VOFF[l] + k*16];
        const float* wrow = &sh_wrel[WROFF[l] + p*256 + tc];
        #pragma unroll
        for (int c=0; c<16; c++)
          acc += rrow[c] * wrow[c*16];
      }
    }
    out[OUT_OFF[l] + ((size_t)bi*(2*l+1) + k)*TAU + tc] = acc;
    sh_acc[t] = acc;
  }
  __syncthreads();
  if (t < 48) {
    const int ll = t>>4, q = t&15;
    const int n = 2*ll+1;
    float a = 0.f;
    for (int i=0;i<n;i++) a += sh_acc[VOFF[ll] + i*16 + q];
    sh_lred[t] = a;
  }
  __syncthreads();
  if (t < 3) {
    float a = 0.f;
    #pragma unroll
    for (int q=0;q<16;q++) a += sh_lred[t*16+q];
    part[t*512 + bi] = a;   // plain store — zero contention
  }
}

// ---------------- K3: redundant partial-reduce + normalize ----------------
__global__ __launch_bounds__(256)
void k_norm(float* __restrict__ out, const float* __restrict__ part){
  __shared__ float sh_r[96];
  __shared__ float sh_d[3];
  const int t = threadIdx.x;
  if (t < 96){
    const int l = t>>5, q = t&31;
    const float* p = part + l*512 + q*16;
    float a=0.f;
    #pragma unroll
    for (int i=0;i<16;i++) a += p[i];
    sh_r[t] = a;
  }
  __syncthreads();
  if (t < 3){
    float a=0.f;
    const float* r = &sh_r[t*32];
    #pragma unroll
    for (int i=0;i<32;i++) a += r[i];
    sh_d[t] = a;
  }
  __syncthreads();
  const int idx = blockIdx.x*256 + t;
  if (idx < 73728){
    const int l = (idx < 8192) ? 0 : (idx < 32768) ? 1 : 2;
    out[idx] = out[idx] / sh_d[l];
  }
}

extern "C" void kernel_launch(void* const* d_in, const int* in_sizes, int n_in,
                              void* d_out, int out_size, void* d_ws, size_t ws_size,
                              hipStream_t stream) {
  // setup_inputs order: v0,s0,wnl0,wrel0, v1,s1,wnl1,wrel1, v2,s2,wnl2,wrel2, conn
  const float* v0    = (const float*)d_in[0];
  const float* s0    = (const float*)d_in[1];
  const float* wnl0  = (const float*)d_in[2];
  const float* wrel0 = (const float*)d_in[3];
  const float* v1    = (const float*)d_in[4];
  const float* s1    = (const float*)d_in[5];
  const float* wnl1  = (const float*)d_in[6];
  const float* wrel1 = (const float*)d_in[7];
  const float* v2    = (const float*)d_in[8];
  const float* s2    = (const float*)d_in[9];
  const float* wnl2  = (const float*)d_in[10];
  const float* wrel2 = (const float*)d_in[11];
  const int*   conn  = (const int*)d_in[12];
  float* out = (float*)d_out;
  float* ws  = (float*)d_ws;
  float* part = ws + PART_OFF;

  k_prep<<<1039, 512, 0, stream>>>(v0, v1, v2, s0, s1, s2,
                                   wnl0, wnl1, wnl2, conn, ws);
  k_main<<<512, 512, 0, stream>>>(wrel0, wrel1, wrel2, ws, out, part);
  k_norm<<<288, 256, 0, stream>>>(out, part);
}

// Round 9
// 106.835 us; speedup vs baseline: 1.2573x; 1.0267x over previous
//
#include <hip/hip_runtime.h>

// CGLayer: MAX_L=2, B=2, N=256, TAU=16 — 3-kernel pipeline.
// Identity: sum_j of edge-level CG(rep, sph) commutes with the j-sum because rep is
// broadcast along j => per-node work after S[bi][m2] = sum_j s[bi][j][m2].
// Round-9: phase B = ONE build (all 51 CG rows, compile-time CG literals) + ONE
// barrier-free mix region (weight loads pipeline under FMAs); k_prep fused to 512 blocks.

#define TAU 16

// ws layout (floats)
#define PART_OFF 768      // 3*512 per-block partial sums [l][bi]
#define VMP_OFF  4096     // 512*144
#define S_OFF    77824    // 512*16 (9 used)
#define WT_OFF   86016    // 15*4096 transposed wnl tiles [tile][tc][cd]

// ---------------- compile-time CG table ----------------
constexpr double cfact(int n){ double r=1.0; for(int i=2;i<=n;i++) r*=i; return r; }
constexpr double csqrt(double x){
  if (x<=0.0) return 0.0;
  double g = x<1.0 ? 1.0 : x;
  for (int i=0;i<80;i++) g = 0.5*(g + x/g);
  return g;
}
constexpr double cg_c(int j1,int j2,int j3,int m1,int m2,int m3){
  if (m1+m2 != m3) return 0.0;
  double pre = csqrt((2.0*j3+1.0)*cfact(j3+j1-j2)*cfact(j3-j1+j2)*cfact(j1+j2-j3)/cfact(j1+j2+j3+1));
  pre *= csqrt(cfact(j3+m3)*cfact(j3-m3)*cfact(j1-m1)*cfact(j1+m1)*cfact(j2-m2)*cfact(j2+m2));
  int kmin = 0;
  if (j2-j3-m1 > kmin) kmin = j2-j3-m1;
  if (j1-j3+m2 > kmin) kmin = j1-j3+m2;
  int kmax = j1+j2-j3;
  if (j1-m1 < kmax) kmax = j1-m1;
  if (j2+m2 < kmax) kmax = j2+m2;
  double s = 0.0;
  for (int k=kmin;k<=kmax;k++){
    double d = cfact(k)*cfact(j1+j2-j3-k)*cfact(j1-m1-k)*cfact(j2+m2-k)*cfact(j3-j2+m1+k)*cfact(j3-j1-m2+k);
    s += (k & 1) ? (-1.0/d) : (1.0/d);
  }
  return pre*s;
}
struct CGTab { float v[615]; };
constexpr CGTab gen_cg(){
  CGTab t{};
  const int TRI[15][3] = {
    {0,0,0},{0,1,1},{0,2,2},{1,0,1},{1,1,0},{1,1,1},{1,1,2},{1,2,1},{1,2,2},
    {2,0,2},{2,1,1},{2,1,2},{2,2,0},{2,2,1},{2,2,2}};
  int off = 0;
  for (int tr=0;tr<15;tr++){
    const int l1=TRI[tr][0], l2=TRI[tr][1], l=TRI[tr][2];
    for (int i1=0;i1<2*l1+1;i1++)
      for (int i2=0;i2<2*l2+1;i2++)
        for (int ik=0;ik<2*l+1;ik++)
          t.v[off++] = (float)cg_c(l1,l2,l,i1-l1,i2-l2,ik-l);
  }
  return t;
}
constexpr CGTab CG = gen_cg();

constexpr int OFF3[27] = {           // [l1*9 + l2*3 + l] -> cg table offset
  0,-1,-1,  -1,1,-1,   -1,-1,10,
  -1,35,-1, 44,53,80,  -1,125,170,
  -1,-1,245,-1,270,315,390,415,490};
constexpr int PAIRS[3][6][2] = {     // (l1,l2) order per output l (reference concat order)
  {{0,0},{1,1},{2,2},{0,0},{0,0},{0,0}},
  {{0,1},{1,0},{1,1},{1,2},{2,1},{2,2}},
  {{0,2},{1,1},{1,2},{2,0},{2,1},{2,2}}};
constexpr int VOFF[3]   = {0,16,64};
constexpr int SOFF[3]   = {0,1,4};
constexpr int OUT_OFF[3]= {0,8192,32768};
constexpr int NPAIR[3]  = {3,6,6};
constexpr int FOFF[9]   = {0,16,32,48,64,80,96,112,128};
constexpr int WROFF[3]  = {0,768,2304};   // wrel LDS offsets
constexpr int WTL[3]    = {0,12288,36864};// per-l offset into transposed wnl region
constexpr int ROWB[3]   = {0,3,21};       // sh_bm row base per l (3,18,30 rows)

__device__ constexpr int RIDX(int l, int mi){ return l==0 ? 0 : (l==1 ? 1+mi : 4+mi); }

// ---------------- K1: vmp + S + wnl transpose, 512 blocks ----------------
__global__ __launch_bounds__(512)
void k_prep(const float* __restrict__ v0, const float* __restrict__ v1, const float* __restrict__ v2,
            const float* __restrict__ s0, const float* __restrict__ s1, const float* __restrict__ s2,
            const float* __restrict__ wnl0, const float* __restrict__ wnl1, const float* __restrict__ wnl2,
            const int* __restrict__ conn, float* __restrict__ ws)
{
  __shared__ float sh_conn[256];
  __shared__ float sh_v[2][144];
  const int t  = threadIdx.x;
  const int bi = blockIdx.x;        // block == node bi
  const int b  = bi >> 8;

  if (t < 256) sh_conn[t] = (float)conn[((size_t)bi<<8) + t];
  __syncthreads();

  if (t < 288) {
    // vmp half h: sum over j in [h*128, h*128+128)
    const int h = (t >= 144) ? 1 : 0;
    const int tt = t - h*144;
    int l, m, c;
    if (tt < 16)      { l=0; m=0;          c=tt;    }
    else if (tt < 64) { l=1; m=(tt-16)>>4; c=tt&15; }
    else              { l=2; m=(tt-64)>>4; c=tt&15; }
    const float* vl = (l==0) ? v0 : (l==1) ? v1 : v2;
    const int dm = 2*l+1;
    const int stride = dm*TAU;
    const float* base = vl + (((size_t)b*256 + h*128)*dm + m)*TAU + c;
    const float* cr = &sh_conn[h*128];
    float a[8];
    #pragma unroll
    for (int q=0;q<8;q++) a[q]=0.f;
    for (int j=0;j<128;j+=8){
      #pragma unroll
      for (int q=0;q<8;q++) a[q] += cr[j+q]*base[(j+q)*stride];
    }
    sh_v[h][tt] = ((a[0]+a[1])+(a[2]+a[3])) + ((a[4]+a[5])+(a[6]+a[7]));
  } else if (t >= 320 && t < 384) {
    // S[bi][9] = sum_j s_l[bi][j][m] — one wave, shfl reduce
    const int lane = t - 320;
    const float* p0 = s0 + (size_t)bi*256;
    const float* p1 = s1 + (size_t)bi*768;
    const float* p2 = s2 + (size_t)bi*1280;
    float a[9];
    #pragma unroll
    for (int m=0;m<9;m++) a[m]=0.f;
    #pragma unroll
    for (int q=0;q<4;q++){
      const int j = lane + q*64;
      a[0] += p0[j];
      a[1] += p1[3*j+0]; a[2] += p1[3*j+1]; a[3] += p1[3*j+2];
      #pragma unroll
      for (int k=0;k<5;k++) a[4+k] += p2[5*j+k];
    }
    #pragma unroll
    for (int m=0;m<9;m++){
      #pragma unroll
      for (int off=32; off; off>>=1) a[m] += __shfl_xor(a[m], off);
    }
    if (lane == 0) {
      #pragma unroll
      for (int m=0;m<9;m++) ws[S_OFF + (size_t)bi*16 + m] = a[m];
    }
  } else if (t >= 448 && bi < 15) {
    // transpose wnl tile bi: wT[tc][cd] = w[cd][tc]
    const int tile = bi;
    const float* src = (tile<3) ? (wnl0 + (size_t)tile*4096)
                     : (tile<9) ? (wnl1 + (size_t)(tile-3)*4096)
                                : (wnl2 + (size_t)(tile-9)*4096);
    float* dst = ws + WT_OFF + (size_t)tile*4096;
    const int q = t - 448;
    #pragma unroll
    for (int r=0;r<4;r++){
      const int cd = q + r*64;
      const float4 r0 = *(const float4*)(src + cd*16);
      const float4 r1 = *(const float4*)(src + cd*16 + 4);
      const float4 r2 = *(const float4*)(src + cd*16 + 8);
      const float4 r3 = *(const float4*)(src + cd*16 + 12);
      dst[ 0*256+cd]=r0.x; dst[ 1*256+cd]=r0.y; dst[ 2*256+cd]=r0.z; dst[ 3*256+cd]=r0.w;
      dst[ 4*256+cd]=r1.x; dst[ 5*256+cd]=r1.y; dst[ 6*256+cd]=r1.z; dst[ 7*256+cd]=r1.w;
      dst[ 8*256+cd]=r2.x; dst[ 9*256+cd]=r2.y; dst[10*256+cd]=r2.z; dst[11*256+cd]=r2.w;
      dst[12*256+cd]=r3.x; dst[13*256+cd]=r3.y; dst[14*256+cd]=r3.z; dst[15*256+cd]=r3.w;
    }
  }
  __syncthreads();
  if (t < 144) ws[VMP_OFF + (size_t)bi*144 + t] = sh_v[0][t] + sh_v[1][t];
}

// ---------------- K2 helpers ----------------
// build one pair's rows into the unified 51-row tile; CG are compile-time literals
template<int L, int P>
__device__ __forceinline__ void build_p(float* __restrict__ dst,
                                        const float (&v_c)[9], const float (&v_d)[9], int tt){
  constexpr int l1 = PAIRS[L][P][0], l2 = PAIRS[L][P][1];
  constexpr int d2 = 2*l2+1, dkk = 2*L+1;
  constexpr int coff = OFF3[l1*9+l2*3+L];
  constexpr int row0 = ROWB[L] + P*dkk;
  #pragma unroll
  for (int kk=0; kk<dkk; kk++){
    const int m = kk - L;
    float a = 0.f;
    #pragma unroll
    for (int m1=-l1; m1<=l1; m1++){
      const int m2 = m - m1;
      if (m2 >= -l2 && m2 <= l2){
        const float C = CG.v[coff + ((m1+l1)*d2 + (m2+l2))*dkk + kk];
        a += C * v_c[RIDX(l1,m1+l1)] * v_d[RIDX(l2,m2+l2)];
      }
    }
    dst[(row0 + kk)*256 + tt] = a;
  }
}

// mix all pairs of output-l from the prebuilt tile; no barriers inside
template<int L>
__device__ __forceinline__ void mixl(const float* __restrict__ wt, const float* __restrict__ sh_bm,
                                     float* __restrict__ sh_mnl, int ksub, int tc0){
  constexpr int NP = NPAIR[L];
  constexpr int DK = 2*L+1;
  float acc[DK][2];
  #pragma unroll
  for (int k=0;k<DK;k++){ acc[k][0]=0.f; acc[k][1]=0.f; }
  const float* wb = wt + (size_t)tc0*256 + ksub*4;
  #pragma unroll
  for (int p=0;p<NP;p++){
    const float4 w0 = *(const float4*)(wb + (size_t)p*4096);
    const float4 w1 = *(const float4*)(wb + (size_t)p*4096 + 256);
    #pragma unroll
    for (int k=0;k<DK;k++){
      const float4 bk = *(const float4*)&sh_bm[(ROWB[L] + p*DK + k)*256 + ksub*4];
      acc[k][0] += bk.x*w0.x + bk.y*w0.y + bk.z*w0.z + bk.w*w0.w;
      acc[k][1] += bk.x*w1.x + bk.y*w1.y + bk.z*w1.z + bk.w*w1.w;
    }
  }
  #pragma unroll
  for (int k=0;k<DK;k++){
    #pragma unroll
    for (int off=32; off; off>>=1){
      acc[k][0] += __shfl_xor(acc[k][0], off);
      acc[k][1] += __shfl_xor(acc[k][1], off);
    }
  }
  if (ksub == 0) {
    #pragma unroll
    for (int k=0;k<DK;k++){
      sh_mnl[VOFF[L] + k*16 + tc0    ] = acc[k][0];
      sh_mnl[VOFF[L] + k*16 + tc0 + 1] = acc[k][1];
    }
  }
}

// ---------------- K2: per-node CG products + mixing + partial sums ----------------
__global__ __launch_bounds__(512, 2)
void k_main(const float* __restrict__ wrel0, const float* __restrict__ wrel1, const float* __restrict__ wrel2,
            const float* __restrict__ ws, float* __restrict__ out, float* __restrict__ part)
{
  __shared__ __align__(16) float sh_bm[51*256];  // ALL CG rows: l0 0-2, l1 3-20, l2 21-50
  __shared__ float sh_wrel[3840];                // all wrel weights, staged once
  __shared__ float sh_mnl[144];
  __shared__ float sh_S[9];
  __shared__ float sh_rel[6*144];                // [p][f144]
  __shared__ float sh_acc[144];
  __shared__ float sh_lred[48];

  const int t  = threadIdx.x;
  const int bi = blockIdx.x;

  // stage wrel into LDS (coalesced) — consumed in phase C
  for (int i=t; i<3840; i+=512){
    float v;
    if (i < 768)       v = wrel0[i];
    else if (i < 2304) v = wrel1[i-768];
    else               v = wrel2[i-2304];
    sh_wrel[i] = v;
  }
  // per-thread vmp fragments (registers only)
  const int bc = (t>>4)&15, bd = t&15;
  float v_c[9], v_d[9];
  {
    const float* vb = ws + VMP_OFF + (size_t)bi*144;
    #pragma unroll
    for (int r=0;r<9;r++){ v_c[r] = vb[FOFF[r]+bc]; v_d[r] = vb[FOFF[r]+bd]; }
  }
  if (t < 9) sh_S[t] = ws[S_OFF + (size_t)bi*16 + t];

  const int tg = t>>6, ksub = t&63;  // wave = tc-pair, lane = K-chunk
  const int tc0 = tg*2;

  // -------- Phase B: ONE build of all 51 rows, ONE barrier-free mix region --------
  {
    const int tt = t & 255;
    if (t < 256){
      build_p<0,0>(sh_bm,v_c,v_d,tt); build_p<0,1>(sh_bm,v_c,v_d,tt); build_p<0,2>(sh_bm,v_c,v_d,tt);
      build_p<1,0>(sh_bm,v_c,v_d,tt); build_p<1,1>(sh_bm,v_c,v_d,tt); build_p<1,2>(sh_bm,v_c,v_d,tt);
      build_p<2,0>(sh_bm,v_c,v_d,tt); build_p<2,1>(sh_bm,v_c,v_d,tt); build_p<2,2>(sh_bm,v_c,v_d,tt);
    } else {
      build_p<1,3>(sh_bm,v_c,v_d,tt); build_p<1,4>(sh_bm,v_c,v_d,tt); build_p<1,5>(sh_bm,v_c,v_d,tt);
      build_p<2,3>(sh_bm,v_c,v_d,tt); build_p<2,4>(sh_bm,v_c,v_d,tt); build_p<2,5>(sh_bm,v_c,v_d,tt);
    }
  }
  __syncthreads();                   // builds visible (also drains wrel/S/vmp loads)
  mixl<0>(ws + WT_OFF + WTL[0], sh_bm, sh_mnl, ksub, tc0);
  mixl<1>(ws + WT_OFF + WTL[1], sh_bm, sh_mnl, ksub, tc0);
  mixl<2>(ws + WT_OFF + WTL[2], sh_bm, sh_mnl, ksub, tc0);
  __syncthreads();                   // sh_mnl complete

  // -------- Phase C: rel-level CG (j-summed sph) + wrel mixing --------
  int l=0, f=0;
  if (t < 16)       { l=0; f=t;    }
  else if (t < 64)  { l=1; f=t-16; }
  else if (t < 144) { l=2; f=t-64; }
  const int k = f>>4, tc = f&15;

  if (t < 144) {
    const int np = NPAIR[l];
    #pragma unroll
    for (int p=0; p<6; p++) {
      if (p < np) {
        const int l1 = PAIRS[l][p][0], l2 = PAIRS[l][p][1];
        const int d2 = 2*l2+1;
        const int coff = OFF3[l1*9+l2*3+l];
        const int dk = 2*l+1;
        const int m = k - l;
        float a = 0.f;
        const int lo = (-l1 > m-l2) ? -l1 : m-l2;
        const int hi = ( l1 < m+l2) ?  l1 : m+l2;
        #pragma unroll
        for (int m1=-2; m1<=2; m1++) {
          if (m1 >= lo && m1 <= hi) {
            const int m2 = m - m1;
            const float C = CG.v[coff + ((m1+l1)*d2 + (m2+l2))*dk + k];
            a += C * sh_mnl[VOFF[l1] + (m1+l1)*TAU + tc] * sh_S[SOFF[l2] + (m2+l2)];
          }
        }
        sh_rel[p*144 + t] = a;
      }
    }
  }
  __syncthreads();
  if (t < 144) {
    const int np = NPAIR[l];
    float acc = 0.f;
    #pragma unroll
    for (int p=0; p<6; p++) {
      if (p < np) {
        const float* rrow = &sh_rel[p*144 + VOFF[l] + k*16];
        const float* wrow = &sh_wrel[WROFF[l] + p*256 + tc];
        #pragma unroll
        for (int c=0; c<16; c++)
          acc += rrow[c] * wrow[c*16];
      }
    }
    out[OUT_OFF[l] + ((size_t)bi*(2*l+1) + k)*TAU + tc] = acc;
    sh_acc[t] = acc;
  }
  __syncthreads();
  if (t < 48) {
    const int ll = t>>4, q = t&15;
    const int n = 2*ll+1;
    float a = 0.f;
    for (int i=0;i<n;i++) a += sh_acc[VOFF[ll] + i*16 + q];
    sh_lred[t] = a;
  }
  __syncthreads();
  if (t < 3) {
    float a = 0.f;
    #pragma unroll
    for (int q=0;q<16;q++) a += sh_lred[t*16+q];
    part[t*512 + bi] = a;   // plain store — zero contention
  }
}

// ---------------- K3: redundant partial-reduce + normalize ----------------
__global__ __launch_bounds__(256)
void k_norm(float* __restrict__ out, const float* __restrict__ part){
  __shared__ float sh_r[96];
  __shared__ float sh_d[3];
  const int t = threadIdx.x;
  if (t < 96){
    const int l = t>>5, q = t&31;
    const float* p = part + l*512 + q*16;
    float a=0.f;
    #pragma unroll
    for (int i=0;i<16;i++) a += p[i];
    sh_r[t] = a;
  }
  __syncthreads();
  if (t < 3){
    float a=0.f;
    const float* r = &sh_r[t*32];
    #pragma unroll
    for (int i=0;i<32;i++) a += r[i];
    sh_d[t] = a;
  }
  __syncthreads();
  const int idx = blockIdx.x*256 + t;
  if (idx < 73728){
    const int l = (idx < 8192) ? 0 : (idx < 32768) ? 1 : 2;
    out[idx] = out[idx] / sh_d[l];
  }
}

extern "C" void kernel_launch(void* const* d_in, const int* in_sizes, int n_in,
                              void* d_out, int out_size, void* d_ws, size_t ws_size,
                              hipStream_t stream) {
  // setup_inputs order: v0,s0,wnl0,wrel0, v1,s1,wnl1,wrel1, v2,s2,wnl2,wrel2, conn
  const float* v0    = (const float*)d_in[0];
  const float* s0    = (const float*)d_in[1];
  const float* wnl0  = (const float*)d_in[2];
  const float* wrel0 = (const float*)d_in[3];
  const float* v1    = (const float*)d_in[4];
  const float* s1    = (const float*)d_in[5];
  const float* wnl1  = (const float*)d_in[6];
  const float* wrel1 = (const float*)d_in[7];
  const float* v2    = (const float*)d_in[8];
  const float* s2    = (const float*)d_in[9];
  const float* wnl2  = (const float*)d_in[10];
  const float* wrel2 = (const float*)d_in[11];
  const int*   conn  = (const int*)d_in[12];
  float* out = (float*)d_out;
  float* ws  = (float*)d_ws;
  float* part = ws + PART_OFF;

  k_prep<<<512, 512, 0, stream>>>(v0, v1, v2, s0, s1, s2,
                                  wnl0, wnl1, wnl2, conn, ws);
  k_main<<<512, 512, 0, stream>>>(wrel0, wrel1, wrel2, ws, out, part);
  k_norm<<<288, 256, 0, stream>>>(out, part);
}